// Round 9
// baseline (120.446 us; speedup 1.0000x reference)
//
#include <hip/hip_runtime.h>
#include <stdint.h>

#define BATCH 16
#define CIN   128
#define COUT  128
#define IMG_H 64
#define IMG_W 64
#define HW    4096
#define KTOT  1152          // 9*128
#define XH    66
#define XW    66
#define NCQ   16            // ci groups of 8
#define NSTEPS 18           // K-steps of 64 in wt4 layout
#define ASTEP 8192          // A elems per step-tile: 8cq*128co*8e (16 KB)
#define AOFF(u) ((u) * ASTEP)
#define BOFF  16384         // B region start (elems) after A dbuf

typedef __attribute__((ext_vector_type(8))) __bf16 bf16x8;
typedef __attribute__((ext_vector_type(4))) float  f32x4;
typedef __attribute__((address_space(1))) const void* gas_p;
typedef __attribute__((address_space(3))) void*       las_p;

static __device__ __forceinline__ unsigned short f2bf(float f) {
  union { float f; uint32_t u; } c; c.f = f;
  uint32_t r = c.u + 0x7fffu + ((c.u >> 16) & 1u);   // RNE
  return (unsigned short)(r >> 16);
}

static __device__ __forceinline__ void gload_lds16(const unsigned short* g, unsigned short* l) {
  __builtin_amdgcn_global_load_lds((gas_p)g, (las_p)l, 16, 0, 0);
}

// ---- fused prep (unchanged, verified) ----
__global__ void prep_fused(const float* __restrict__ x, const float* __restrict__ w,
                           unsigned short* __restrict__ wt4, unsigned short* __restrict__ xpad) {
  const int t = threadIdx.x;
  if (blockIdx.x < BATCH * IMG_H) {
    __shared__ uint32_t tile[64 * 68];              // [wcol][ci2], pad 68 words
    const int b = blockIdx.x >> 6;
    const int h = blockIdx.x & 63;
    const float* xb = x + (size_t)b * CIN * HW + h * IMG_W;
    uint4* xp4 = (uint4*)xpad;                      // 16B chunks

    const int lane16 = t & 15;
    const int g      = t >> 4;
#pragma unroll
    for (int it = 0; it < 4; ++it) {
      const int ci = it * 32 + g * 2;
      const float4 va = *(const float4*)(xb + (size_t)ci * HW + lane16 * 4);
      const float4 vb = *(const float4*)(xb + (size_t)(ci + 1) * HW + lane16 * 4);
      const float av[4] = {va.x, va.y, va.z, va.w};
      const float bv[4] = {vb.x, vb.y, vb.z, vb.w};
#pragma unroll
      for (int cc = 0; cc < 4; ++cc)
        tile[(lane16 * 4 + cc) * 68 + it * 16 + g] =
            (uint32_t)f2bf(av[cc]) | ((uint32_t)f2bf(bv[cc]) << 16);
    }
    __syncthreads();

    const uint32_t rbase = ((uint32_t)b * XH + h + 1) * NCQ;
#pragma unroll
    for (int it = 0; it < 4; ++it) {
      const int o   = it * 256 + t;
      const int cqg = o >> 6;
      const int wc  = o & 63;
      const uint4 v = *(const uint4*)&tile[wc * 68 + cqg * 4];
      xp4[(rbase + cqg) * XW + wc + 1] = v;
    }
    if (t < 32) {
      const int cqg = t & 15;
      const int col = (t >> 4) ? 65 : 0;
      xp4[(rbase + cqg) * XW + col] = make_uint4(0, 0, 0, 0);
    }
    if (h == 0) {
      const uint32_t r0  = (uint32_t)b * XH * NCQ * XW;
      const uint32_t r65 = ((uint32_t)b * XH + 65) * NCQ * XW;
      for (int i = t; i < NCQ * XW; i += 256) {
        xp4[r0 + i]  = make_uint4(0, 0, 0, 0);
        xp4[r65 + i] = make_uint4(0, 0, 0, 0);
      }
    }
  } else {
    const int idx  = blockIdx.x - BATCH * IMG_H;
    const int b    = idx / NSTEPS;
    const int step = idx % NSTEPS;
    const int khkw = step >> 1;
    const int cib  = (step & 1) << 6;
    const float* wb = w + (size_t)b * COUT * KTOT;
    unsigned short* dst = wt4 + ((size_t)b * NSTEPS + step) * ASTEP;
#pragma unroll
    for (int i = 0; i < 4; ++i) {
      const int c  = i * 256 + t;                 // chunk 0..1023
      const int cq = c >> 7;
      const int co = c & 127;
      const int ci0 = cib + cq * 8;
      const float* src = wb + (size_t)co * KTOT + (size_t)ci0 * 9 + khkw;
      uint32_t p[4];
#pragma unroll
      for (int e = 0; e < 4; ++e)
        p[e] = (uint32_t)f2bf(src[(2 * e) * 9]) | ((uint32_t)f2bf(src[(2 * e + 1) * 9]) << 16);
      *(uint4*)&dst[(size_t)c * 8] = make_uint4(p[0], p[1], p[2], p[3]);
    }
  }
}

// ---- main implicit-GEMM: 128co x 128px per block, 8 waves, K-split ----
// R8 skeleton (16 waves/CU, dbuf A, __syncthreads protocol, LDS K-reduction)
// + kh-PERSISTENT B: B staged once per kh (3x33KB) instead of per step
// (18x16KB); kw is a read offset into the 66-wide persistent rows. Block
// staging 576 -> 389 KB; per-sub-step barrier drains only A's 2 gloads.
__global__ __launch_bounds__(512, 4) void dynconv_gemm(
    const unsigned short* __restrict__ wt4,   // [B][18][8][128][8] bf16
    const unsigned short* __restrict__ xpad,  // [B][66][16][66][8] bf16, halo=0
    float* __restrict__ out) {                // [B][COUT][64][64] fp32
  // [0,16384): A dbuf (2 x 16 KB). [16384, 33280): B_kh [2r][16cq][66][8].
  // Whole array reused as the 64 KB f32 reduce buffer at the end.
  __shared__ alignas(16) unsigned short SH[33280];   // 66560 B

  const int t   = threadIdx.x;
  const int bid = blockIdx.x;
  const int xcd = bid & 7;
  const int idx = bid >> 3;                 // 0..63 within XCD
  const int b   = xcd * 2 + (idx >> 5);     // batch (2 per XCD, slabs in L2)
  const int oh0 = (idx & 31) * 2;           // first of 2 output rows

  const int lane = t & 63;
  const int wave = t >> 6;                  // 0..7
  const int wm   = (wave & 1) << 6;         // co half of wave's tile
  const int wn   = ((wave >> 1) & 1) << 6;  // px half (output row select)
  const int kg   = wave >> 2;               // K-group: cq 0-3 or 4-7
  const int l15  = lane & 15;
  const int quad = lane >> 4;
  const int rsel = (wave >> 1) & 1;         // output row of wave's tile

  const unsigned short* wt4b = wt4 + (size_t)b * NSTEPS * ASTEP;
  const unsigned short* xb   = xpad + (size_t)b * XH * NCQ * XW * 8;

  // ---- A staging: step G (= kh*6 + kw*2 + cqh) into dbuf half U ----
  // chunk c = r*512 + t at elem c*8 (linear wt4 step tile; per-lane src).
#define STAGE_A(U, G)                                                         \
  {                                                                           \
    const unsigned short* astep_ = wt4b + (size_t)(G) * ASTEP;                \
    _Pragma("unroll")                                                         \
    for (int r_ = 0; r_ < 2; ++r_)                                            \
      gload_lds16(astep_ + (size_t)(r_ * 512 + t) * 8,                        \
                  &SH[AOFF(U) + (r_ * 512 + wave * 64) * 8]);                 \
  }

  // ---- B staging: all 2 rows x 16 cq x 66 cols for one kh ----
  // 32 segments; wave stages 4 (cols 0..63 via gload, per-lane src);
  // cols 64,65 via plain load+ds_write by threads t<64 (1 KB total).
#define STAGE_B(KH)                                                           \
  {                                                                           \
    _Pragma("unroll")                                                         \
    for (int k_ = 0; k_ < 4; ++k_) {                                          \
      const int p_   = wave * 4 + k_;                                         \
      const int row_ = p_ >> 4;                                               \
      const int cq_  = p_ & 15;                                               \
      const unsigned short* src_ = xb +                                       \
          ((size_t)((oh0 + row_ + (KH)) * NCQ + cq_) * XW + lane) * 8;        \
      gload_lds16(src_, &SH[BOFF + p_ * (XW * 8)]);                           \
    }                                                                         \
    if (t < 64) {                                                             \
      const int seg_ = t >> 1;                                                \
      const int c64_ = 64 + (t & 1);                                          \
      const int row_ = seg_ >> 4;                                             \
      const int cq_  = seg_ & 15;                                             \
      const uint4 v_ = *(const uint4*)(xb +                                   \
          ((size_t)((oh0 + row_ + (KH)) * NCQ + cq_) * XW + c64_) * 8);       \
      *(uint4*)&SH[BOFF + (seg_ * XW + c64_) * 8] = v_;                       \
    }                                                                         \
  }

  f32x4 acc[4][4] = {};

  STAGE_B(0);
  STAGE_A(0, 0);
  __syncthreads();

  for (int kh = 0; kh < 3; ++kh) {
#pragma unroll 2
    for (int ss = 0; ss < 6; ++ss) {
      const int g  = kh * 6 + ss;
      const int u  = ss & 1;                 // kh*6 is even
      const int kw = ss >> 1;
      const int cqh = ss & 1;
      if (g < NSTEPS - 1) STAGE_A(u ^ 1, g + 1);   // prefetch next A step

      const int cql = kg * 4 + quad;         // wave's cq within the step
      bf16x8 af[4], bf[4];
#pragma unroll
      for (int i = 0; i < 4; ++i)
        af[i] = *(const bf16x8*)&SH[AOFF(u) + (cql * 128 + wm + i * 16 + l15) * 8];
#pragma unroll
      for (int j = 0; j < 4; ++j)
        bf[j] = *(const bf16x8*)&SH[BOFF +
            ((rsel * 16 + cqh * 8 + cql) * XW + kw + j * 16 + l15) * 8];
#pragma unroll
      for (int i = 0; i < 4; ++i)
#pragma unroll
        for (int j = 0; j < 4; ++j)
          acc[i][j] = __builtin_amdgcn_mfma_f32_16x16x32_bf16(af[i], bf[j], acc[i][j], 0, 0, 0);

      __syncthreads();   // drains A prefetch + protects dbuf halves & B
    }
    if (kh < 2) {
      STAGE_B(kh + 1);   // previous kh's B fully consumed (post-barrier)
      __syncthreads();   // drain B stage before compute resumes
    }
  }
#undef STAGE_A
#undef STAGE_B

  // ---- cross-wave K-reduction through LDS (verified R8 pattern) ----
  // lane-rotated 16B slots dodge the 256B-stride bank conflict; static
  // chunk index keeps acc[] register-resident (rule #20).
  float* red = (float*)&SH[0];   // 64 KB = 4 waves x 64 lanes x 64 f32
  if (wave >= 4) {
    float* row = red + (size_t)((wave - 4) * 64 + lane) * 64;
#pragma unroll
    for (int m = 0; m < 16; ++m)
      *(f32x4*)&row[((m + lane) & 15) * 4] = acc[m >> 2][m & 3];
  }
  __syncthreads();
  if (wave < 4) {
    const float* row = red + (size_t)(wave * 64 + lane) * 64;
#pragma unroll
    for (int m = 0; m < 16; ++m) {
      const f32x4 v = *(const f32x4*)&row[((m + lane) & 15) * 4];
      acc[m >> 2][m & 3] += v;
    }

    // epilogue (verified R5/R8 algebra)
    float* obase = out + (size_t)b * COUT * HW + (size_t)(oh0 + (wn >> 6)) * IMG_W;
#pragma unroll
    for (int i = 0; i < 4; ++i) {
#pragma unroll
      for (int r = 0; r < 4; ++r) {
        const int co = wm + i * 16 + quad * 4 + r;
        float* orow = obase + (size_t)co * HW;
#pragma unroll
        for (int j = 0; j < 4; ++j)
          orow[j * 16 + l15] = acc[i][j][r];
      }
    }
  }
}

// ---- safety net: direct fp32 conv ----
__global__ void dynconv_naive(const float* __restrict__ x, const float* __restrict__ w,
                              float* __restrict__ out) {
  const int o   = blockIdx.x * 256 + threadIdx.x;
  const int pix = o & (HW - 1);
  const int co  = (o >> 12) & (COUT - 1);
  const int b   = o >> 19;
  const int oh  = pix >> 6, ow = pix & 63;
  const float* xb = x + (size_t)b * CIN * HW;
  const float* wb = w + ((size_t)b * COUT + co) * CIN * 9;
  float s = 0.f;
  for (int ci = 0; ci < CIN; ++ci) {
    const float* xc = xb + ci * HW;
    const float* wc = wb + ci * 9;
#pragma unroll
    for (int kh = 0; kh < 3; ++kh) {
      const int ih = oh + kh - 1;
      if ((unsigned)ih >= IMG_H) continue;
#pragma unroll
      for (int kw = 0; kw < 3; ++kw) {
        const int iw = ow + kw - 1;
        if ((unsigned)iw >= IMG_W) continue;
        s += xc[ih * IMG_W + iw] * wc[kh * 3 + kw];
      }
    }
  }
  out[o] = s;
}

extern "C" void kernel_launch(void* const* d_in, const int* in_sizes, int n_in,
                              void* d_out, int out_size, void* d_ws, size_t ws_size,
                              hipStream_t stream) {
  const float* x = (const float*)d_in[0];
  const float* w = (const float*)d_in[1];
  float* out = (float*)d_out;

  const size_t wt_bytes = (size_t)BATCH * NSTEPS * ASTEP * sizeof(unsigned short);       //  4.72 MB
  const size_t xp_bytes = (size_t)BATCH * XH * NCQ * XW * 8 * sizeof(unsigned short);    // 17.84 MB

  if (ws_size >= wt_bytes + xp_bytes) {
    unsigned short* wt4  = (unsigned short*)d_ws;
    unsigned short* xpad = (unsigned short*)((char*)d_ws + wt_bytes);
    prep_fused<<<BATCH * IMG_H + BATCH * NSTEPS, 256, 0, stream>>>(x, w, wt4, xpad);
    dynconv_gemm<<<512, 512, 0, stream>>>(wt4, xpad, out);
  } else {
    dynconv_naive<<<(BATCH * COUT * HW) / 256, 256, 0, stream>>>(x, w, out);
  }
}